// Round 17
// baseline (229.725 us; speedup 1.0000x reference)
//
#include <hip/hip_runtime.h>
#include <hip/hip_bf16.h>
#include <math.h>

namespace {

typedef __hip_bfloat16 bf16;
typedef unsigned short u16;
typedef __bf16 bf8v __attribute__((ext_vector_type(8)));
typedef float f4v __attribute__((ext_vector_type(4)));
typedef short s8v __attribute__((ext_vector_type(8)));
typedef u16 u4v __attribute__((ext_vector_type(4)));

constexpr int Bb = 2;
constexpr int Ll = 2048;
constexpr int DM = 768;
constexpr int DI = 1536;          // 2*768
constexpr int DS = 16;
constexpr int RK = 48;
constexpr int XD = RK + 2 * DS;   // 80
constexpr int Mrows = Bb * Ll;    // 4096
constexpr int NC = 32;            // scan chunks
constexpr int CL = Ll / NC;       // 64 steps per chunk
constexpr float LOG2E = 1.44269504f;

// padded bf16 weight shapes
constexpr int NW1 = 2 * DI * DM;      // in_proj  [3072][768]
constexpr int NWX = 128 * DI;         // x_proj   [128][1536] (rows 80+ = 0)
constexpr int NWD = DI * 64;          // dt_proj  [1536][64]  (cols 48+ = 0)
constexpr int NWO = DM * DI;          // out_proj [768][1536]
constexpr int NWC = DI * 4;           // conv_w   [1536][4]
constexpr int NWCB = DI;              // conv_b   [1536]

__device__ inline float b2f(bf16 v) { return __bfloat162float(v); }
__device__ inline bf16 f2b(float v) { return __float2bfloat16(v); }

union BfBits { bf16 h; u16 u; };
__device__ inline u16 f2u(float v) {
  BfBits bb; bb.h = __float2bfloat16(v); return bb.u;
}
__device__ inline float u2f(u16 u) {
  BfBits bb; bb.u = u; return b2f(bb.h);
}

// Load element i of an EXTERNAL input tensor (dtype runtime-detected).
__device__ inline float ldx(const void* p, size_t i, int bf) {
  if (bf) return __bfloat162float(((const bf16*)p)[i]);
  return ((const float*)p)[i];
}

// async global->LDS, 16 B per lane. LDS dest = base + lane*16 (HW rule).
__device__ inline void gload16(const void* g, u16* lds) {
  __builtin_amdgcn_global_load_lds(
      (__attribute__((address_space(1))) void*)g,
      (__attribute__((address_space(3))) void*)lds, 16, 0, 0);
}

// scan LDS row permutation: spreads transpose-staging writes across banks.
__device__ inline int rperm(int d) {
  return (d & 56) | ((d ^ (d >> 3)) & 7);
}

// ---- dtype probe: do low 16 bits of words look like bf16 values? ----
__global__ void detect_kernel(const unsigned int* __restrict__ xw,
                              int* __restrict__ flag) {
  int t = threadIdx.x;  // 64 lanes
  unsigned int w = xw[t];
  unsigned int lo = w & 0xFFFFu;
  unsigned int ef = (lo >> 7) & 0xFFu;
  bool plaus = (lo == 0u) || (ef >= 104u && ef <= 136u);
  unsigned long long m = __ballot(plaus);
  if (t == 0) flag[0] = (__popcll(m) >= 48) ? 1 : 0;
}

// ---- convert weights: w_in | w_x | w_dt | dtA-pad | w_cv | w_cb ------
__global__ __launch_bounds__(256) void convert_w1(
    const void* __restrict__ in_proj, const void* __restrict__ x_proj,
    const void* __restrict__ dt_proj, const void* __restrict__ conv_w,
    const void* __restrict__ conv_b,
    bf16* __restrict__ w_in, bf16* __restrict__ w_x, bf16* __restrict__ w_dt,
    bf16* __restrict__ dtA, bf16* __restrict__ w_cv, bf16* __restrict__ w_cb,
    const int* __restrict__ flagp) {
  int bf = flagp[0];
  int e = (blockIdx.x * 256 + threadIdx.x) * 4;
  if (e < NW1) {
    u4v v;
#pragma unroll
    for (int k = 0; k < 4; ++k) v[k] = f2u(ldx(in_proj, e + k, bf));
    *(u4v*)&w_in[e] = v;
    return;
  }
  e -= NW1;
  if (e < NWX) {
    int r = e / DI, c = e % DI;
    u4v v = {};
    if (r < 80) {
#pragma unroll
      for (int k = 0; k < 4; ++k) v[k] = f2u(ldx(x_proj, (size_t)r * DI + c + k, bf));
    }
    *(u4v*)&w_x[e] = v;
    return;
  }
  e -= NWX;
  if (e < NWD) {
    int r = e / 64, c = e % 64;
    u4v v = {};
#pragma unroll
    for (int k = 0; k < 4; ++k)
      if (c + k < RK) v[k] = f2u(ldx(dt_proj, (size_t)r * RK + c + k, bf));
    *(u4v*)&w_dt[e] = v;
    return;
  }
  e -= NWD;
  if (e < Mrows * 16) {  // zero dtA pad cols 48..63
    int row = e / 16, col = RK + (e % 16);
    u4v v = {};
    *(u4v*)&dtA[(size_t)row * 64 + col] = v;
    return;
  }
  e -= Mrows * 16;
  if (e < NWC) {
    u4v v;
#pragma unroll
    for (int k = 0; k < 4; ++k) v[k] = f2u(ldx(conv_w, e + k, bf));
    *(u4v*)&w_cv[e] = v;
    return;
  }
  e -= NWC;
  if (e < NWCB) {
    u4v v;
#pragma unroll
    for (int k = 0; k < 4; ++k) v[k] = f2u(ldx(conv_b, e + k, bf));
    *(u4v*)&w_cb[e] = v;
  }
}

// ---- convert out_proj after scan (into dead carry region) ----
__global__ __launch_bounds__(256) void convert_w2(
    const void* __restrict__ out_proj, bf16* __restrict__ w_out,
    const int* __restrict__ flagp) {
  int bf = flagp[0];
  int e = (blockIdx.x * 256 + threadIdx.x) * 4;
  if (e >= NWO) return;
  u4v v;
#pragma unroll
  for (int k = 0; k < 4; ++k) v[k] = f2u(ldx(out_proj, e + k, bf));
  *(u4v*)&w_out[e] = v;
}

// ---------------- LayerNorm: one block per row of 768, bf16 out -------
__global__ __launch_bounds__(256) void ln_kernel(
    const void* __restrict__ x, const void* __restrict__ w,
    const void* __restrict__ b, bf16* __restrict__ xn,
    const int* __restrict__ flagp) {
  int bf = flagp[0];
  int row = blockIdx.x;
  int t = threadIdx.x;
  float v[3];
  float s = 0.f, ss = 0.f;
#pragma unroll
  for (int i = 0; i < 3; ++i) {
    v[i] = ldx(x, (size_t)row * DM + t + i * 256, bf);
    s += v[i];
    ss += v[i] * v[i];
  }
#pragma unroll
  for (int off = 32; off; off >>= 1) {
    s += __shfl_down(s, off);
    ss += __shfl_down(ss, off);
  }
  __shared__ float sb[4], ssb[4];
  int wid = t >> 6, lid = t & 63;
  if (lid == 0) { sb[wid] = s; ssb[wid] = ss; }
  __syncthreads();
  if (t == 0) {
    sb[0] = sb[0] + sb[1] + sb[2] + sb[3];
    ssb[0] = ssb[0] + ssb[1] + ssb[2] + ssb[3];
  }
  __syncthreads();
  float mu = sb[0] * (1.f / DM);
  float var = ssb[0] * (1.f / DM) - mu * mu;
  float rs = rsqrtf(var + 1e-5f);
#pragma unroll
  for (int i = 0; i < 3; ++i) {
    int c = t + i * 256;
    xn[(size_t)row * DM + c] =
        f2b((v[i] - mu) * rs * ldx(w, c, bf) + ldx(b, c, bf));
  }
}

// ---- MFMA GEMM, global_load_lds staging, BK=64 (2 sub-tiles/barrier) --
template <int EPI, int BM>
__global__ __launch_bounds__(256, 3) void gemm_gl(
    int M, int N, int klen,
    const bf16* __restrict__ A, int lda,
    const bf16* __restrict__ Bw, int ldb,
    void* __restrict__ Cv, void* __restrict__ Cv2, int ldc,
    const void* __restrict__ extra,
    const int* __restrict__ flagp) {
  constexpr int FI = BM / 32;          // A-frags per wave
  __shared__ __align__(16) u16 As[2][BM * 32];
  __shared__ __align__(16) u16 Bs[2][128 * 32];
  int tid = threadIdx.x;
  int l = tid & 63, w = tid >> 6;
  int wr = w >> 1, wc = w & 1;
  int m0 = blockIdx.y * BM, n0 = blockIdx.x * 128;
  int kbeg = blockIdx.z * klen;
  int nt = klen / 64;
  int lr = l & 15, lk = (l >> 4) * 8;
  f4v acc[FI][4] = {};

  int srow = l >> 2, schunk = l & 3;

  for (int t = 0; t < nt; ++t) {
    __syncthreads();   // all waves done reading previous tiles
#pragma unroll
    for (int h = 0; h < 2; ++h) {
      int k0 = kbeg + t * 64 + h * 32;
#pragma unroll
      for (int c = 0; c < BM / 64; ++c) {
        int seg = w + c * 4;
        int row = seg * 16 + srow;
        int gcol = k0 + ((schunk ^ ((row >> 1) & 3)) << 3);
        gload16(A + (size_t)(m0 + row) * lda + gcol, &As[h][seg * 512]);
      }
#pragma unroll
      for (int c = 0; c < 2; ++c) {
        int seg = w + c * 4;
        int row = seg * 16 + srow;
        int gcol = k0 + ((schunk ^ ((row >> 1) & 3)) << 3);
        gload16(Bw + (size_t)(n0 + row) * ldb + gcol, &Bs[h][seg * 512]);
      }
    }
    __syncthreads();   // drains vmcnt(0) -> both halves ready
#pragma unroll
    for (int h = 0; h < 2; ++h) {
      bf8v af[FI], bfv[4];
#pragma unroll
      for (int i = 0; i < FI; ++i) {
        int row = wr * (BM / 2) + i * 16 + lr;
        af[i] = *(const bf8v*)&As[h][row * 32 + (((lk >> 3) ^ ((row >> 1) & 3)) << 3)];
      }
#pragma unroll
      for (int j = 0; j < 4; ++j) {
        int row = wc * 64 + j * 16 + lr;
        bfv[j] = *(const bf8v*)&Bs[h][row * 32 + (((lk >> 3) ^ ((row >> 1) & 3)) << 3)];
      }
#pragma unroll
      for (int i = 0; i < FI; ++i)
#pragma unroll
        for (int j = 0; j < 4; ++j)
          acc[i][j] = __builtin_amdgcn_mfma_f32_16x16x32_bf16(
              af[i], bfv[j], acc[i][j], 0, 0, 0);
    }
  }

  int bf = flagp[0];
  int lq = l >> 4;
  size_t pbase = (size_t)blockIdx.z * M * ldc;
#pragma unroll
  for (int i = 0; i < FI; ++i) {
#pragma unroll
    for (int j = 0; j < 4; ++j) {
      int nn = n0 + wc * 64 + j * 16 + lr;
      if (nn >= N) continue;
#pragma unroll
      for (int r = 0; r < 4; ++r) {
        int m = m0 + wr * (BM / 2) + i * 16 + lq * 4 + r;
        float v = acc[i][j][r];
        size_t ci = (size_t)m * ldc + nn;
        if (EPI == 0) {
          ((float*)Cv)[pbase + ci] = v;
        } else if (EPI == 1) {
          float tt = v + ldx(extra, nn, bf);
          float sp = (tt > 20.f) ? tt : log1pf(__expf(tt));
          ((bf16*)Cv)[ci] = f2b(sp);
        } else if (EPI == 4) {
          if (nn < DI) ((bf16*)Cv)[(size_t)m * DI + nn] = f2b(v);
          else ((bf16*)Cv2)[(size_t)m * DI + nn - DI] = f2b(v);
        }
      }
    }
  }
}

// ---- reduce 8 f32 partials -> bf16 xdbl [4096,80] + padded dtA [4096,64]
__global__ __launch_bounds__(256) void reduce_xdbl(
    const float* __restrict__ part, bf16* __restrict__ xdbl,
    bf16* __restrict__ dtA) {
  int idx = blockIdx.x * 256 + threadIdx.x;
  if (idx >= Mrows * XD) return;
  float s = 0.f;
#pragma unroll
  for (int k = 0; k < 8; ++k) s += part[(size_t)k * Mrows * XD + idx];
  bf16 v = f2b(s);
  xdbl[idx] = v;
  int col = idx % XD;
  if (col < RK) dtA[(size_t)(idx / XD) * 64 + col] = v;
}

// ---- reduce 2 f32 partials + residual -> f32 out [4096,768] ----
__global__ __launch_bounds__(256) void reduce_out(
    const float* __restrict__ part, const void* __restrict__ x,
    float* __restrict__ out, const int* __restrict__ flagp) {
  int bf = flagp[0];
  int idx = blockIdx.x * 256 + threadIdx.x;
  if (idx >= Mrows * DM) return;
  out[idx] = part[idx] + part[(size_t)Mrows * DM + idx] + ldx(x, idx, bf);
}

// ------- depthwise causal conv + bias + SiLU, 8 d per thread ----------
__global__ __launch_bounds__(256) void conv_silu_kernel(
    const bf16* __restrict__ xin, const bf16* __restrict__ w_cv,
    const bf16* __restrict__ w_cb, bf16* __restrict__ xc) {
  int idx = blockIdx.x * 256 + threadIdx.x;   // over Mrows*DI/8
  if (idx >= Mrows * DI / 8) return;
  int d0 = (idx % (DI / 8)) * 8;
  int m = idx / (DI / 8);
  int l = m % Ll;
  s8v wv[4];
#pragma unroll
  for (int q = 0; q < 4; ++q)
    wv[q] = *(const s8v*)(w_cv + (size_t)d0 * 4 + q * 8);
  s8v cbv = *(const s8v*)(w_cb + d0);
  float acc[8];
#pragma unroll
  for (int k = 0; k < 8; ++k) acc[k] = u2f((u16)cbv[k]);
#pragma unroll
  for (int j = 0; j < 4; ++j) {
    int lj = l - 3 + j;
    if (lj < 0) continue;
    s8v xv = *(const s8v*)(xin + (size_t)(m - 3 + j) * DI + d0);
#pragma unroll
    for (int k = 0; k < 8; ++k)
      acc[k] += u2f((u16)wv[(k * 4 + j) >> 3][(k * 4 + j) & 7]) * u2f((u16)xv[k]);
  }
  s8v o;
#pragma unroll
  for (int k = 0; k < 8; ++k) {
    float v = acc[k] / (1.f + __expf(-acc[k]));
    o[k] = (short)f2u(v);
  }
  *(s8v*)(xc + (size_t)m * DI + d0) = o;
}

// ====== chunked selective scan: register-state, 4 lanes per d ======
// carry layout: [((b*NC + c)*DI + d)*16 + n], f32 (RAW local carries).
constexpr int TS = 72;  // LDS row stride (u16) per d: 144B, 16B-aligned

// Phase 1: local scan from h=0; ap via exp2(sum dv).
__global__ __launch_bounds__(256) void scan_p1(
    const bf16* __restrict__ delta, const bf16* __restrict__ xc,
    const bf16* __restrict__ xdbl, const void* __restrict__ A_log,
    float* __restrict__ ca, float* __restrict__ cb,
    const int* __restrict__ flagp) {
  int bf = flagp[0];
  int tid = threadIdx.x;
  int bx = blockIdx.x;             // b*NC + c
  int b = bx / NC, c = bx % NC;
  int dq = tid >> 2, n4 = tid & 3;
  int d0 = blockIdx.y * 64;
  int d = d0 + dq;
  __shared__ float Bsh[CL * 16];   // 4 KB
  __shared__ __align__(16) u16 dT[64 * TS];  // 9 KB, [perm(d)][row]
  __shared__ __align__(16) u16 xT[64 * TS];  // 9 KB
  size_t base = (size_t)b * Ll + c * CL;
  {
    int e = tid * 4;               // B staging: 1024 entries / 256 thr
    int l = e >> 4, n = e & 15;
    size_t row = base + l;
    u4v v = *(const u4v*)((const u16*)xdbl + row * XD + RK + n);
#pragma unroll
    for (int k = 0; k < 4; ++k) Bsh[e + k] = u2f(v[k]);
  }
  {  // transpose-stage delta/xc: thread = rows 2lh,2lh+1 x 8 d (permuted)
    int lh = tid >> 3;
    int dd0 = (tid & 7) * 8;
    const u16* dg = (const u16*)delta + (base + 2 * lh) * DI + d0 + dd0;
    const u16* xg = (const u16*)xc + (base + 2 * lh) * DI + d0 + dd0;
    s8v d0v = *(const s8v*)dg;
    s8v d1v = *(const s8v*)(dg + DI);
    s8v x0v = *(const s8v*)xg;
    s8v x1v = *(const s8v*)(xg + DI);
#pragma unroll
    for (int k = 0; k < 8; ++k) {
      int rr = rperm(dd0 + k);
      unsigned int dw = (unsigned int)(u16)d0v[k] |
                        ((unsigned int)(u16)d1v[k] << 16);
      *(unsigned int*)&dT[rr * TS + 2 * lh] = dw;
      dw = (unsigned int)(u16)x0v[k] |
           ((unsigned int)(u16)x1v[k] << 16);
      *(unsigned int*)&xT[rr * TS + 2 * lh] = dw;
    }
  }
  __syncthreads();
  int rq = rperm(dq);
  float An2[4], h[4] = {};
  float sdv = 0.f;
#pragma unroll
  for (int k = 0; k < 4; ++k)
    An2[k] = -__expf(ldx(A_log, (size_t)d * DS + n4 * 4 + k, bf)) * LOG2E;
  for (int l0 = 0; l0 < CL; l0 += 8) {
    s8v dvv = *(const s8v*)&dT[rq * TS + l0];
    s8v xvv = *(const s8v*)&xT[rq * TS + l0];
    float dv[8], xcv[8];
#pragma unroll
    for (int k2 = 0; k2 < 8; ++k2) {
      dv[k2] = u2f((u16)dvv[k2]);
      xcv[k2] = u2f((u16)xvv[k2]);
    }
    f4v bvv[8];
#pragma unroll
    for (int j = 0; j < 8; ++j)
      bvv[j] = *(const f4v*)&Bsh[(l0 + j) * 16 + n4 * 4];
#pragma unroll
    for (int j = 0; j < 8; ++j) {
      float dx = dv[j] * xcv[j];
      sdv += dv[j];
#pragma unroll
      for (int k = 0; k < 4; ++k) {
        float dA = exp2f(dv[j] * An2[k]);
        h[k] = dA * h[k] + dx * bvv[j][k];
      }
    }
  }
  size_t cbase = ((size_t)bx * DI + d) * 16 + n4 * 4;
  f4v av, hv;
#pragma unroll
  for (int k = 0; k < 4; ++k) {
    av[k] = exp2f(sdv * An2[k]);   // prod of dA == exp2(sum(dv)*An2)
    hv[k] = h[k];
  }
  *(f4v*)&ca[cbase] = av;
  *(f4v*)&cb[cbase] = hv;
}

// Phase 3 (p2 fused): fold own carry prefix, recompute local scan,
// round-robin gate, emit y (in-place over delta).
__global__ __launch_bounds__(256) void scan_p3(
    bf16* dy, const bf16* __restrict__ xc,
    const bf16* __restrict__ xdbl, const bf16* __restrict__ z,
    const void* __restrict__ A_log, const void* __restrict__ Dp,
    const float* __restrict__ ca, const float* __restrict__ cb,
    const int* __restrict__ flagp) {
  int bf = flagp[0];
  int tid = threadIdx.x;
  int bx = blockIdx.x;             // b*NC + c
  int b = bx / NC, c = bx % NC;
  int dq = tid >> 2, n4 = tid & 3;
  int d0 = blockIdx.y * 64;
  int d = d0 + dq;
  __shared__ float BCsh[CL * 32];  // 8 KB: [B(16) | C(16)] per row
  __shared__ __align__(16) u16 dT[64 * TS];  // 9 KB
  __shared__ __align__(16) u16 xT[64 * TS];  // 9 KB
  size_t base = (size_t)b * Ll + c * CL;
  {
    int e = tid * 8;               // BC staging: 2048 entries / 256 thr
    int l = e >> 5, j = e & 31;
    size_t row = base + l;
    s8v v = *(const s8v*)((const u16*)xdbl + row * XD + RK + j);
#pragma unroll
    for (int k = 0; k < 8; ++k) BCsh[e + k] = u2f((u16)v[k]);
  }
  {  // transpose-stage delta/xc (permuted rows)
    int lh = tid >> 3;
    int dd0 = (tid & 7) * 8;
    const u16* dg = (const u16*)dy + (base + 2 * lh) * DI + d0 + dd0;
    const u16* xg = (const u16*)xc + (base + 2 * lh) * DI + d0 + dd0;
    s8v d0v = *(const s8v*)dg;
    s8v d1v = *(const s8v*)(dg + DI);
    s8v x0v = *(const s8v*)xg;
    s8v x1v = *(const s8v*)(xg + DI);
#pragma unroll
    for (int k = 0; k < 8; ++k) {
      int rr = rperm(dd0 + k);
      unsigned int dw = (unsigned int)(u16)d0v[k] |
                        ((unsigned int)(u16)d1v[k] << 16);
      *(unsigned int*)&dT[rr * TS + 2 * lh] = dw;
      dw = (unsigned int)(u16)x0v[k] |
           ((unsigned int)(u16)x1v[k] << 16);
      *(unsigned int*)&xT[rr * TS + 2 * lh] = dw;
    }
  }
  // fused p2: fold raw carries of chunks 0..c-1 -> h_init (overlaps staging)
  float h[4] = {};
  size_t coff = (size_t)d * 16 + n4 * 4;
  for (int cc = 0; cc < c; ++cc) {
    size_t cbase2 = (size_t)(b * NC + cc) * DI * 16 + coff;
    f4v av = *(const f4v*)&ca[cbase2];
    f4v bv = *(const f4v*)&cb[cbase2];
#pragma unroll
    for (int k = 0; k < 4; ++k) h[k] = av[k] * h[k] + bv[k];
  }
  __syncthreads();
  int rq = rperm(dq);
  float An2[4];
#pragma unroll
  for (int k = 0; k < 4; ++k)
    An2[k] = -__expf(ldx(A_log, (size_t)d * DS + n4 * 4 + k, bf)) * LOG2E;
  float Dv = ldx(Dp, d, bf);
  bf16* dp = dy + base * DI + d;
  const bf16* zp = z + base * DI + d;
  for (int l0 = 0; l0 < CL; l0 += 8) {
    s8v dvv = *(const s8v*)&dT[rq * TS + l0];
    s8v xvv = *(const s8v*)&xT[rq * TS + l0];
    float dv[8], xcv[8];
#pragma unroll
    for (int k2 = 0; k2 < 8; ++k2) {
      dv[k2] = u2f((u16)dvv[k2]);
      xcv[k2] = u2f((u16)xvv[k2]);
    }
    // per-lane gate rows: l0+n4 and l0+4+n4
    float zg0 = b2f(zp[(size_t)(l0 + n4) * DI]);
    float zg1 = b2f(zp[(size_t)(l0 + 4 + n4) * DI]);
#pragma unroll
    for (int half = 0; half < 2; ++half) {
      f4v bvv[4], cvv[4];
#pragma unroll
      for (int jj = 0; jj < 4; ++jj) {
        int j = half * 4 + jj;
        bvv[jj] = *(const f4v*)&BCsh[(l0 + j) * 32 + n4 * 4];
        cvv[jj] = *(const f4v*)&BCsh[(l0 + j) * 32 + 16 + n4 * 4];
      }
      float accK = 0.f, xg = 0.f;
#pragma unroll
      for (int jj = 0; jj < 4; ++jj) {
        int j = half * 4 + jj;
        float dx = dv[j] * xcv[j];
        float acc = 0.f;
#pragma unroll
        for (int k = 0; k < 4; ++k) {
          float dA = exp2f(dv[j] * An2[k]);
          h[k] = dA * h[k] + dx * bvv[jj][k];
          acc += h[k] * cvv[jj][k];
        }
        acc += __shfl_xor(acc, 1, 4);
        acc += __shfl_xor(acc, 2, 4);
        if (n4 == jj) { accK = acc; xg = xcv[j]; }
      }
      float zg = half ? zg1 : zg0;
      float yv = (accK + xg * Dv) * (zg / (1.f + __expf(-zg)));
      dp[(size_t)(l0 + half * 4 + n4) * DI] = f2b(yv);
    }
  }
}

}  // namespace

extern "C" void kernel_launch(void* const* d_in, const int* in_sizes, int n_in,
                              void* d_out, int out_size, void* d_ws, size_t ws_size,
                              hipStream_t stream) {
  const void* x        = d_in[0];
  const void* in_proj  = d_in[1];
  const void* conv_w   = d_in[2];
  const void* conv_b   = d_in[3];
  const void* x_proj   = d_in[4];
  const void* dt_proj  = d_in[5];
  const void* dt_b     = d_in[6];
  const void* A_log    = d_in[7];
  const void* Dp       = d_in[8];
  const void* out_proj = d_in[9];
  const void* ln_w     = d_in[10];
  const void* ln_b     = d_in[11];
  float* out = (float*)d_out;  // reference output dtype: float32

  // ws layout (~56.3 MB)
  char* wsc = (char*)d_ws;
  int* flag = (int*)wsc;
  bf16* xn   = (bf16*)(wsc + 256);             // [4096,768]
  bf16* buf1 = xn + (size_t)Mrows * DM;        // [4096,1536]: xin->delta->y
  bf16* z    = buf1 + (size_t)Mrows * DI;
  bf16* xc   = z + (size_t)Mrows * DI;
  bf16* xdbl = xc + (size_t)Mrows * DI;        // [4096,80]
  float* carry_b = (float*)(xdbl + (size_t)Mrows * XD);   // 6.29 MB
  bf16* dtA = (bf16*)((float*)carry_b + (size_t)Bb * NC * DI * 16);
  bf16* w_in = dtA + (size_t)Mrows * 64;       // 4.72 MB
  bf16* w_cv = w_in + (size_t)NW1;             // 12 KB
  bf16* w_cb = w_cv + (size_t)NWC;             // 3 KB
  float* carry_a = (float*)xn;      // xn dead after in_proj GEMM
  bf16* w_out = (bf16*)xn;          // converted after scan (carry_a dead)
  bf16* w_x  = (bf16*)carry_b;      // alive until scan_p1 overwrites
  bf16* w_dt = w_x + (size_t)NWX;
  float* part8 = (float*)buf1;      // x_proj partials
  float* part2 = (float*)z;         // out_proj partials

  detect_kernel<<<1, 64, 0, stream>>>((const unsigned int*)x, flag);
  {
    int quads = (NW1 + NWX + NWD + Mrows * 16 + NWC + NWCB) / 4;
    convert_w1<<<(quads + 255) / 256, 256, 0, stream>>>(
        in_proj, x_proj, dt_proj, conv_w, conv_b,
        w_in, w_x, w_dt, dtA, w_cv, w_cb, flag);
  }
  ln_kernel<<<Mrows, 256, 0, stream>>>(x, ln_w, ln_b, xn, flag);
  // fused in_proj: [xin | z] = xn @ w_in^T   (N=3072, K=768)
  gemm_gl<4, 128><<<dim3(2 * DI / 128, Mrows / 128, 1), 256, 0, stream>>>(
      Mrows, 2 * DI, DM, xn, DM, w_in, DM, buf1, z, DI, nullptr, flag);
  conv_silu_kernel<<<(Mrows * DI / 8) / 256, 256, 0, stream>>>(
      buf1, w_cv, w_cb, xc);
  // x_proj split-K=8 (klen=192): A=xc, B=w_x[128,1536] -> part8
  gemm_gl<0, 64><<<dim3(1, Mrows / 64, 8), 256, 0, stream>>>(
      Mrows, XD, DI / 8, xc, DI, w_x, DI, part8, nullptr, XD, nullptr, flag);
  reduce_xdbl<<<(Mrows * XD + 255) / 256, 256, 0, stream>>>(part8, xdbl, dtA);
  // delta = softplus(dtA @ w_dt^T + dt_b) -> buf1 (K padded to 64)
  gemm_gl<1, 64><<<dim3(DI / 128, Mrows / 64, 1), 256, 0, stream>>>(
      Mrows, DI, 64, dtA, 64, w_dt, 64, buf1, nullptr, DI, dt_b, flag);
  // chunked scan: p1 (local) then p3 (prefix-fused + emit)
  scan_p1<<<dim3(Bb * NC, DI / 64), 256, 0, stream>>>(
      buf1, xc, xdbl, A_log, carry_a, carry_b, flag);
  scan_p3<<<dim3(Bb * NC, DI / 64), 256, 0, stream>>>(
      buf1, xc, xdbl, z, A_log, Dp, carry_a, carry_b, flag);
  // convert out_proj into dead carry_a region, then out_proj split-K=2
  convert_w2<<<(NWO / 4 + 255) / 256, 256, 0, stream>>>(out_proj, w_out, flag);
  gemm_gl<0, 64><<<dim3(DM / 128, Mrows / 64, 2), 256, 0, stream>>>(
      Mrows, DM, DI / 2, buf1, DI, w_out, DI, part2, nullptr, DM, nullptr, flag);
  reduce_out<<<(Mrows * DM + 255) / 256, 256, 0, stream>>>(part2, x, out, flag);
}

// Round 18
// 220.466 us; speedup vs baseline: 1.0420x; 1.0420x over previous
//
#include <hip/hip_runtime.h>
#include <hip/hip_bf16.h>
#include <math.h>

namespace {

typedef __hip_bfloat16 bf16;
typedef unsigned short u16;
typedef __bf16 bf8v __attribute__((ext_vector_type(8)));
typedef float f4v __attribute__((ext_vector_type(4)));
typedef short s8v __attribute__((ext_vector_type(8)));
typedef u16 u4v __attribute__((ext_vector_type(4)));

constexpr int Bb = 2;
constexpr int Ll = 2048;
constexpr int DM = 768;
constexpr int DI = 1536;          // 2*768
constexpr int DS = 16;
constexpr int RK = 48;
constexpr int XD = RK + 2 * DS;   // 80
constexpr int Mrows = Bb * Ll;    // 4096
constexpr int NC = 32;            // scan chunks
constexpr int CL = Ll / NC;       // 64 steps per chunk
constexpr float LOG2E = 1.44269504f;

// padded bf16 weight shapes
constexpr int NW1 = 2 * DI * DM;      // in_proj  [3072][768]
constexpr int NWX = 128 * DI;         // x_proj   [128][1536] (rows 80+ = 0)
constexpr int NWD = DI * 64;          // dt_proj  [1536][64]  (cols 48+ = 0)
constexpr int NWO = DM * DI;          // out_proj [768][1536]
constexpr int NWC = DI * 4;           // conv_w   [1536][4]
constexpr int NWCB = DI;              // conv_b   [1536]

__device__ inline float b2f(bf16 v) { return __bfloat162float(v); }
__device__ inline bf16 f2b(float v) { return __float2bfloat16(v); }

union BfBits { bf16 h; u16 u; };
__device__ inline u16 f2u(float v) {
  BfBits bb; bb.h = __float2bfloat16(v); return bb.u;
}
__device__ inline float u2f(u16 u) {
  BfBits bb; bb.u = u; return b2f(bb.h);
}

// Load element i of an EXTERNAL input tensor (dtype runtime-detected).
__device__ inline float ldx(const void* p, size_t i, int bf) {
  if (bf) return __bfloat162float(((const bf16*)p)[i]);
  return ((const float*)p)[i];
}

// async global->LDS, 16 B per lane. LDS dest = base + lane*16 (HW rule).
__device__ inline void gload16(const void* g, u16* lds) {
  __builtin_amdgcn_global_load_lds(
      (__attribute__((address_space(1))) void*)g,
      (__attribute__((address_space(3))) void*)lds, 16, 0, 0);
}

// scan LDS row permutation: spreads transpose-staging writes across banks.
__device__ inline int rperm(int d) {
  return (d & 56) | ((d ^ (d >> 3)) & 7);
}

// ---- dtype probe: do low 16 bits of words look like bf16 values? ----
__global__ void detect_kernel(const unsigned int* __restrict__ xw,
                              int* __restrict__ flag) {
  int t = threadIdx.x;  // 64 lanes
  unsigned int w = xw[t];
  unsigned int lo = w & 0xFFFFu;
  unsigned int ef = (lo >> 7) & 0xFFu;
  bool plaus = (lo == 0u) || (ef >= 104u && ef <= 136u);
  unsigned long long m = __ballot(plaus);
  if (t == 0) flag[0] = (__popcll(m) >= 48) ? 1 : 0;
}

// ---- convert weights: w_in | w_x | w_dt | dtA-pad | w_cv | w_cb ------
__global__ __launch_bounds__(256) void convert_w1(
    const void* __restrict__ in_proj, const void* __restrict__ x_proj,
    const void* __restrict__ dt_proj, const void* __restrict__ conv_w,
    const void* __restrict__ conv_b,
    bf16* __restrict__ w_in, bf16* __restrict__ w_x, bf16* __restrict__ w_dt,
    bf16* __restrict__ dtA, bf16* __restrict__ w_cv, bf16* __restrict__ w_cb,
    const int* __restrict__ flagp) {
  int bf = flagp[0];
  int e = (blockIdx.x * 256 + threadIdx.x) * 4;
  if (e < NW1) {
    u4v v;
#pragma unroll
    for (int k = 0; k < 4; ++k) v[k] = f2u(ldx(in_proj, e + k, bf));
    *(u4v*)&w_in[e] = v;
    return;
  }
  e -= NW1;
  if (e < NWX) {
    int r = e / DI, c = e % DI;
    u4v v = {};
    if (r < 80) {
#pragma unroll
      for (int k = 0; k < 4; ++k) v[k] = f2u(ldx(x_proj, (size_t)r * DI + c + k, bf));
    }
    *(u4v*)&w_x[e] = v;
    return;
  }
  e -= NWX;
  if (e < NWD) {
    int r = e / 64, c = e % 64;
    u4v v = {};
#pragma unroll
    for (int k = 0; k < 4; ++k)
      if (c + k < RK) v[k] = f2u(ldx(dt_proj, (size_t)r * RK + c + k, bf));
    *(u4v*)&w_dt[e] = v;
    return;
  }
  e -= NWD;
  if (e < Mrows * 16) {  // zero dtA pad cols 48..63
    int row = e / 16, col = RK + (e % 16);
    u4v v = {};
    *(u4v*)&dtA[(size_t)row * 64 + col] = v;
    return;
  }
  e -= Mrows * 16;
  if (e < NWC) {
    u4v v;
#pragma unroll
    for (int k = 0; k < 4; ++k) v[k] = f2u(ldx(conv_w, e + k, bf));
    *(u4v*)&w_cv[e] = v;
    return;
  }
  e -= NWC;
  if (e < NWCB) {
    u4v v;
#pragma unroll
    for (int k = 0; k < 4; ++k) v[k] = f2u(ldx(conv_b, e + k, bf));
    *(u4v*)&w_cb[e] = v;
  }
}

// ---- convert out_proj after scan (into dead carry_a region) ----
__global__ __launch_bounds__(256) void convert_w2(
    const void* __restrict__ out_proj, bf16* __restrict__ w_out,
    const int* __restrict__ flagp) {
  int bf = flagp[0];
  int e = (blockIdx.x * 256 + threadIdx.x) * 4;
  if (e >= NWO) return;
  u4v v;
#pragma unroll
  for (int k = 0; k < 4; ++k) v[k] = f2u(ldx(out_proj, e + k, bf));
  *(u4v*)&w_out[e] = v;
}

// ---------------- LayerNorm: one block per row of 768, bf16 out -------
__global__ __launch_bounds__(256) void ln_kernel(
    const void* __restrict__ x, const void* __restrict__ w,
    const void* __restrict__ b, bf16* __restrict__ xn,
    const int* __restrict__ flagp) {
  int bf = flagp[0];
  int row = blockIdx.x;
  int t = threadIdx.x;
  float v[3];
  float s = 0.f, ss = 0.f;
#pragma unroll
  for (int i = 0; i < 3; ++i) {
    v[i] = ldx(x, (size_t)row * DM + t + i * 256, bf);
    s += v[i];
    ss += v[i] * v[i];
  }
#pragma unroll
  for (int off = 32; off; off >>= 1) {
    s += __shfl_down(s, off);
    ss += __shfl_down(ss, off);
  }
  __shared__ float sb[4], ssb[4];
  int wid = t >> 6, lid = t & 63;
  if (lid == 0) { sb[wid] = s; ssb[wid] = ss; }
  __syncthreads();
  if (t == 0) {
    sb[0] = sb[0] + sb[1] + sb[2] + sb[3];
    ssb[0] = ssb[0] + ssb[1] + ssb[2] + ssb[3];
  }
  __syncthreads();
  float mu = sb[0] * (1.f / DM);
  float var = ssb[0] * (1.f / DM) - mu * mu;
  float rs = rsqrtf(var + 1e-5f);
#pragma unroll
  for (int i = 0; i < 3; ++i) {
    int c = t + i * 256;
    xn[(size_t)row * DM + c] =
        f2b((v[i] - mu) * rs * ldx(w, c, bf) + ldx(b, c, bf));
  }
}

// ---- MFMA GEMM, global_load_lds staging, BK=64 (2 sub-tiles/barrier) --
template <int EPI, int BM>
__global__ __launch_bounds__(256, 3) void gemm_gl(
    int M, int N, int klen,
    const bf16* __restrict__ A, int lda,
    const bf16* __restrict__ Bw, int ldb,
    void* __restrict__ Cv, void* __restrict__ Cv2, int ldc,
    const void* __restrict__ extra,
    const int* __restrict__ flagp) {
  constexpr int FI = BM / 32;          // A-frags per wave
  __shared__ __align__(16) u16 As[2][BM * 32];
  __shared__ __align__(16) u16 Bs[2][128 * 32];
  int tid = threadIdx.x;
  int l = tid & 63, w = tid >> 6;
  int wr = w >> 1, wc = w & 1;
  int m0 = blockIdx.y * BM, n0 = blockIdx.x * 128;
  int kbeg = blockIdx.z * klen;
  int nt = klen / 64;
  int lr = l & 15, lk = (l >> 4) * 8;
  f4v acc[FI][4] = {};

  int srow = l >> 2, schunk = l & 3;

  for (int t = 0; t < nt; ++t) {
    __syncthreads();   // all waves done reading previous tiles
#pragma unroll
    for (int h = 0; h < 2; ++h) {
      int k0 = kbeg + t * 64 + h * 32;
#pragma unroll
      for (int c = 0; c < BM / 64; ++c) {
        int seg = w + c * 4;
        int row = seg * 16 + srow;
        int gcol = k0 + ((schunk ^ ((row >> 1) & 3)) << 3);
        gload16(A + (size_t)(m0 + row) * lda + gcol, &As[h][seg * 512]);
      }
#pragma unroll
      for (int c = 0; c < 2; ++c) {
        int seg = w + c * 4;
        int row = seg * 16 + srow;
        int gcol = k0 + ((schunk ^ ((row >> 1) & 3)) << 3);
        gload16(Bw + (size_t)(n0 + row) * ldb + gcol, &Bs[h][seg * 512]);
      }
    }
    __syncthreads();   // drains vmcnt(0) -> both halves ready
#pragma unroll
    for (int h = 0; h < 2; ++h) {
      bf8v af[FI], bfv[4];
#pragma unroll
      for (int i = 0; i < FI; ++i) {
        int row = wr * (BM / 2) + i * 16 + lr;
        af[i] = *(const bf8v*)&As[h][row * 32 + (((lk >> 3) ^ ((row >> 1) & 3)) << 3)];
      }
#pragma unroll
      for (int j = 0; j < 4; ++j) {
        int row = wc * 64 + j * 16 + lr;
        bfv[j] = *(const bf8v*)&Bs[h][row * 32 + (((lk >> 3) ^ ((row >> 1) & 3)) << 3)];
      }
#pragma unroll
      for (int i = 0; i < FI; ++i)
#pragma unroll
        for (int j = 0; j < 4; ++j)
          acc[i][j] = __builtin_amdgcn_mfma_f32_16x16x32_bf16(
              af[i], bfv[j], acc[i][j], 0, 0, 0);
    }
  }

  int bf = flagp[0];
  int lq = l >> 4;
  size_t pbase = (size_t)blockIdx.z * M * ldc;
#pragma unroll
  for (int i = 0; i < FI; ++i) {
#pragma unroll
    for (int j = 0; j < 4; ++j) {
      int nn = n0 + wc * 64 + j * 16 + lr;
      if (nn >= N) continue;
#pragma unroll
      for (int r = 0; r < 4; ++r) {
        int m = m0 + wr * (BM / 2) + i * 16 + lq * 4 + r;
        float v = acc[i][j][r];
        size_t ci = (size_t)m * ldc + nn;
        if (EPI == 0) {
          ((float*)Cv)[pbase + ci] = v;
        } else if (EPI == 1) {
          float tt = v + ldx(extra, nn, bf);
          float sp = (tt > 20.f) ? tt : log1pf(__expf(tt));
          ((bf16*)Cv)[ci] = f2b(sp);
        } else if (EPI == 4) {
          if (nn < DI) ((bf16*)Cv)[(size_t)m * DI + nn] = f2b(v);
          else ((bf16*)Cv2)[(size_t)m * DI + nn - DI] = f2b(v);
        }
      }
    }
  }
}

// ---- reduce 8 f32 partials -> bf16 xdbl [4096,80] + padded dtA [4096,64]
__global__ __launch_bounds__(256) void reduce_xdbl(
    const float* __restrict__ part, bf16* __restrict__ xdbl,
    bf16* __restrict__ dtA) {
  int idx = blockIdx.x * 256 + threadIdx.x;
  if (idx >= Mrows * XD) return;
  float s = 0.f;
#pragma unroll
  for (int k = 0; k < 8; ++k) s += part[(size_t)k * Mrows * XD + idx];
  bf16 v = f2b(s);
  xdbl[idx] = v;
  int col = idx % XD;
  if (col < RK) dtA[(size_t)(idx / XD) * 64 + col] = v;
}

// ---- reduce 2 f32 partials + residual -> f32 out [4096,768] ----
__global__ __launch_bounds__(256) void reduce_out(
    const float* __restrict__ part, const void* __restrict__ x,
    float* __restrict__ out, const int* __restrict__ flagp) {
  int bf = flagp[0];
  int idx = blockIdx.x * 256 + threadIdx.x;
  if (idx >= Mrows * DM) return;
  out[idx] = part[idx] + part[(size_t)Mrows * DM + idx] + ldx(x, idx, bf);
}

// ------- depthwise causal conv + bias + SiLU, 8 d per thread ----------
__global__ __launch_bounds__(256) void conv_silu_kernel(
    const bf16* __restrict__ xin, const bf16* __restrict__ w_cv,
    const bf16* __restrict__ w_cb, bf16* __restrict__ xc) {
  int idx = blockIdx.x * 256 + threadIdx.x;   // over Mrows*DI/8
  if (idx >= Mrows * DI / 8) return;
  int d0 = (idx % (DI / 8)) * 8;
  int m = idx / (DI / 8);
  int l = m % Ll;
  s8v wv[4];
#pragma unroll
  for (int q = 0; q < 4; ++q)
    wv[q] = *(const s8v*)(w_cv + (size_t)d0 * 4 + q * 8);
  s8v cbv = *(const s8v*)(w_cb + d0);
  float acc[8];
#pragma unroll
  for (int k = 0; k < 8; ++k) acc[k] = u2f((u16)cbv[k]);
#pragma unroll
  for (int j = 0; j < 4; ++j) {
    int lj = l - 3 + j;
    if (lj < 0) continue;
    s8v xv = *(const s8v*)(xin + (size_t)(m - 3 + j) * DI + d0);
#pragma unroll
    for (int k = 0; k < 8; ++k)
      acc[k] += u2f((u16)wv[(k * 4 + j) >> 3][(k * 4 + j) & 7]) * u2f((u16)xv[k]);
  }
  s8v o;
#pragma unroll
  for (int k = 0; k < 8; ++k) {
    float v = acc[k] / (1.f + __expf(-acc[k]));
    o[k] = (short)f2u(v);
  }
  *(s8v*)(xc + (size_t)m * DI + d0) = o;
}

// ====== chunked selective scan: register-state, 4 lanes per d ======
// carry layout: [((b*NC + c)*DI + d)*16 + n], f32.
constexpr int TS = 72;  // LDS row stride (u16) per d: 144B, 16B-aligned

// Phase 1: local scan from h=0; ap via exp2(sum dv).
__global__ __launch_bounds__(256) void scan_p1(
    const bf16* __restrict__ delta, const bf16* __restrict__ xc,
    const bf16* __restrict__ xdbl, const void* __restrict__ A_log,
    float* __restrict__ ca, float* __restrict__ cb,
    const int* __restrict__ flagp) {
  int bf = flagp[0];
  int tid = threadIdx.x;
  int bx = blockIdx.x;             // b*NC + c
  int b = bx / NC, c = bx % NC;
  int dq = tid >> 2, n4 = tid & 3;
  int d0 = blockIdx.y * 64;
  int d = d0 + dq;
  __shared__ float Bsh[CL * 16];   // 4 KB
  __shared__ __align__(16) u16 dT[64 * TS];  // 9 KB, [perm(d)][row]
  __shared__ __align__(16) u16 xT[64 * TS];  // 9 KB
  size_t base = (size_t)b * Ll + c * CL;
  {
    int e = tid * 4;               // B staging: 1024 entries / 256 thr
    int l = e >> 4, n = e & 15;
    size_t row = base + l;
    u4v v = *(const u4v*)((const u16*)xdbl + row * XD + RK + n);
#pragma unroll
    for (int k = 0; k < 4; ++k) Bsh[e + k] = u2f(v[k]);
  }
  {  // transpose-stage delta/xc: thread = rows 2lh,2lh+1 x 8 d (permuted)
    int lh = tid >> 3;
    int dd0 = (tid & 7) * 8;
    const u16* dg = (const u16*)delta + (base + 2 * lh) * DI + d0 + dd0;
    const u16* xg = (const u16*)xc + (base + 2 * lh) * DI + d0 + dd0;
    s8v d0v = *(const s8v*)dg;
    s8v d1v = *(const s8v*)(dg + DI);
    s8v x0v = *(const s8v*)xg;
    s8v x1v = *(const s8v*)(xg + DI);
#pragma unroll
    for (int k = 0; k < 8; ++k) {
      int rr = rperm(dd0 + k);
      unsigned int dw = (unsigned int)(u16)d0v[k] |
                        ((unsigned int)(u16)d1v[k] << 16);
      *(unsigned int*)&dT[rr * TS + 2 * lh] = dw;
      dw = (unsigned int)(u16)x0v[k] |
           ((unsigned int)(u16)x1v[k] << 16);
      *(unsigned int*)&xT[rr * TS + 2 * lh] = dw;
    }
  }
  __syncthreads();
  int rq = rperm(dq);
  float An2[4], h[4] = {};
  float sdv = 0.f;
#pragma unroll
  for (int k = 0; k < 4; ++k)
    An2[k] = -__expf(ldx(A_log, (size_t)d * DS + n4 * 4 + k, bf)) * LOG2E;
  for (int l0 = 0; l0 < CL; l0 += 8) {
    s8v dvv = *(const s8v*)&dT[rq * TS + l0];
    s8v xvv = *(const s8v*)&xT[rq * TS + l0];
    float dv[8], xcv[8];
#pragma unroll
    for (int k2 = 0; k2 < 8; ++k2) {
      dv[k2] = u2f((u16)dvv[k2]);
      xcv[k2] = u2f((u16)xvv[k2]);
    }
    f4v bvv[8];
#pragma unroll
    for (int j = 0; j < 8; ++j)
      bvv[j] = *(const f4v*)&Bsh[(l0 + j) * 16 + n4 * 4];
#pragma unroll
    for (int j = 0; j < 8; ++j) {
      float dx = dv[j] * xcv[j];
      sdv += dv[j];
#pragma unroll
      for (int k = 0; k < 4; ++k) {
        float dA = exp2f(dv[j] * An2[k]);
        h[k] = dA * h[k] + dx * bvv[j][k];
      }
    }
  }
  size_t cbase = ((size_t)bx * DI + d) * 16 + n4 * 4;
  f4v av, hv;
#pragma unroll
  for (int k = 0; k < 4; ++k) {
    av[k] = exp2f(sdv * An2[k]);   // prod of dA == exp2(sum(dv)*An2)
    hv[k] = h[k];
  }
  *(f4v*)&ca[cbase] = av;
  *(f4v*)&cb[cbase] = hv;
}

// Phase 2: sequential scan over chunk carries -> h_init per chunk
__global__ __launch_bounds__(256) void scan_p2(
    const float* __restrict__ ca, float* __restrict__ cb) {
  int tid = threadIdx.x;
  int bx = blockIdx.x;             // b*(DI/64) + dblk
  int b = bx / (DI / 64);
  int d = (bx % (DI / 64)) * 64 + (tid >> 2);
  int n4 = tid & 3;
  size_t off = (size_t)d * 16 + n4 * 4;
  f4v h = {};
  for (int c = 0; c < NC; ++c) {
    size_t cbase = (size_t)(b * NC + c) * DI * 16 + off;
    f4v av = *(const f4v*)&ca[cbase];
    f4v bv = *(const f4v*)&cb[cbase];
    f4v hv = h;
#pragma unroll
    for (int k = 0; k < 4; ++k) h[k] = av[k] * h[k] + bv[k];
    *(f4v*)&cb[cbase] = hv;
  }
}

// Phase 3: recompute from h_init; round-robin gate; permuted LDS tiles.
__global__ __launch_bounds__(256) void scan_p3(
    bf16* dy, const bf16* __restrict__ xc,
    const bf16* __restrict__ xdbl, const bf16* __restrict__ z,
    const void* __restrict__ A_log, const void* __restrict__ Dp,
    const float* __restrict__ cb, const int* __restrict__ flagp) {
  int bf = flagp[0];
  int tid = threadIdx.x;
  int bx = blockIdx.x;             // b*NC + c
  int b = bx / NC, c = bx % NC;
  int dq = tid >> 2, n4 = tid & 3;
  int d0 = blockIdx.y * 64;
  int d = d0 + dq;
  __shared__ float BCsh[CL * 32];  // 8 KB: [B(16) | C(16)] per row
  __shared__ __align__(16) u16 dT[64 * TS];  // 9 KB
  __shared__ __align__(16) u16 xT[64 * TS];  // 9 KB
  size_t base = (size_t)b * Ll + c * CL;
  {
    int e = tid * 8;               // BC staging: 2048 entries / 256 thr
    int l = e >> 5, j = e & 31;
    size_t row = base + l;
    s8v v = *(const s8v*)((const u16*)xdbl + row * XD + RK + j);
#pragma unroll
    for (int k = 0; k < 8; ++k) BCsh[e + k] = u2f((u16)v[k]);
  }
  {  // transpose-stage delta/xc (permuted rows)
    int lh = tid >> 3;
    int dd0 = (tid & 7) * 8;
    const u16* dg = (const u16*)dy + (base + 2 * lh) * DI + d0 + dd0;
    const u16* xg = (const u16*)xc + (base + 2 * lh) * DI + d0 + dd0;
    s8v d0v = *(const s8v*)dg;
    s8v d1v = *(const s8v*)(dg + DI);
    s8v x0v = *(const s8v*)xg;
    s8v x1v = *(const s8v*)(xg + DI);
#pragma unroll
    for (int k = 0; k < 8; ++k) {
      int rr = rperm(dd0 + k);
      unsigned int dw = (unsigned int)(u16)d0v[k] |
                        ((unsigned int)(u16)d1v[k] << 16);
      *(unsigned int*)&dT[rr * TS + 2 * lh] = dw;
      dw = (unsigned int)(u16)x0v[k] |
           ((unsigned int)(u16)x1v[k] << 16);
      *(unsigned int*)&xT[rr * TS + 2 * lh] = dw;
    }
  }
  __syncthreads();
  int rq = rperm(dq);
  float An2[4], h[4];
  size_t cbase = ((size_t)bx * DI + d) * 16 + n4 * 4;
  {
    f4v hv = *(const f4v*)&cb[cbase];
#pragma unroll
    for (int k = 0; k < 4; ++k) h[k] = hv[k];
  }
#pragma unroll
  for (int k = 0; k < 4; ++k)
    An2[k] = -__expf(ldx(A_log, (size_t)d * DS + n4 * 4 + k, bf)) * LOG2E;
  float Dv = ldx(Dp, d, bf);
  bf16* dp = dy + base * DI + d;
  const bf16* zp = z + base * DI + d;
  for (int l0 = 0; l0 < CL; l0 += 8) {
    s8v dvv = *(const s8v*)&dT[rq * TS + l0];
    s8v xvv = *(const s8v*)&xT[rq * TS + l0];
    float dv[8], xcv[8];
#pragma unroll
    for (int k2 = 0; k2 < 8; ++k2) {
      dv[k2] = u2f((u16)dvv[k2]);
      xcv[k2] = u2f((u16)xvv[k2]);
    }
    // per-lane gate rows: l0+n4 and l0+4+n4
    float zg0 = b2f(zp[(size_t)(l0 + n4) * DI]);
    float zg1 = b2f(zp[(size_t)(l0 + 4 + n4) * DI]);
#pragma unroll
    for (int half = 0; half < 2; ++half) {
      f4v bvv[4], cvv[4];
#pragma unroll
      for (int jj = 0; jj < 4; ++jj) {
        int j = half * 4 + jj;
        bvv[jj] = *(const f4v*)&BCsh[(l0 + j) * 32 + n4 * 4];
        cvv[jj] = *(const f4v*)&BCsh[(l0 + j) * 32 + 16 + n4 * 4];
      }
      float accK = 0.f, xg = 0.f;
#pragma unroll
      for (int jj = 0; jj < 4; ++jj) {
        int j = half * 4 + jj;
        float dx = dv[j] * xcv[j];
        float acc = 0.f;
#pragma unroll
        for (int k = 0; k < 4; ++k) {
          float dA = exp2f(dv[j] * An2[k]);
          h[k] = dA * h[k] + dx * bvv[jj][k];
          acc += h[k] * cvv[jj][k];
        }
        acc += __shfl_xor(acc, 1, 4);
        acc += __shfl_xor(acc, 2, 4);
        if (n4 == jj) { accK = acc; xg = xcv[j]; }
      }
      float zg = half ? zg1 : zg0;
      float yv = (accK + xg * Dv) * (zg / (1.f + __expf(-zg)));
      dp[(size_t)(l0 + half * 4 + n4) * DI] = f2b(yv);
    }
  }
}

}  // namespace

extern "C" void kernel_launch(void* const* d_in, const int* in_sizes, int n_in,
                              void* d_out, int out_size, void* d_ws, size_t ws_size,
                              hipStream_t stream) {
  const void* x        = d_in[0];
  const void* in_proj  = d_in[1];
  const void* conv_w   = d_in[2];
  const void* conv_b   = d_in[3];
  const void* x_proj   = d_in[4];
  const void* dt_proj  = d_in[5];
  const void* dt_b     = d_in[6];
  const void* A_log    = d_in[7];
  const void* Dp       = d_in[8];
  const void* out_proj = d_in[9];
  const void* ln_w     = d_in[10];
  const void* ln_b     = d_in[11];
  float* out = (float*)d_out;  // reference output dtype: float32

  // ws layout (~56.3 MB)
  char* wsc = (char*)d_ws;
  int* flag = (int*)wsc;
  bf16* xn   = (bf16*)(wsc + 256);             // [4096,768]
  bf16* buf1 = xn + (size_t)Mrows * DM;        // [4096,1536]: xin->delta->y
  bf16* z    = buf1 + (size_t)Mrows * DI;
  bf16* xc   = z + (size_t)Mrows * DI;
  bf16* xdbl = xc + (size_t)Mrows * DI;        // [4096,80]
  float* carry_b = (float*)(xdbl + (size_t)Mrows * XD);   // 6.29 MB
  bf16* dtA = (bf16*)((float*)carry_b + (size_t)Bb * NC * DI * 16);
  bf16* w_in = dtA + (size_t)Mrows * 64;       // 4.72 MB
  bf16* w_cv = w_in + (size_t)NW1;             // 12 KB
  bf16* w_cb = w_cv + (size_t)NWC;             // 3 KB
  float* carry_a = (float*)xn;      // xn dead after in_proj GEMM
  bf16* w_out = (bf16*)xn;          // converted after scan (carry_a dead)
  bf16* w_x  = (bf16*)carry_b;      // alive until scan_p1 overwrites
  bf16* w_dt = w_x + (size_t)NWX;
  float* part8 = (float*)buf1;      // x_proj partials
  float* part2 = (float*)z;         // out_proj partials

  detect_kernel<<<1, 64, 0, stream>>>((const unsigned int*)x, flag);
  {
    int quads = (NW1 + NWX + NWD + Mrows * 16 + NWC + NWCB) / 4;
    convert_w1<<<(quads + 255) / 256, 256, 0, stream>>>(
        in_proj, x_proj, dt_proj, conv_w, conv_b,
        w_in, w_x, w_dt, dtA, w_cv, w_cb, flag);
  }
  ln_kernel<<<Mrows, 256, 0, stream>>>(x, ln_w, ln_b, xn, flag);
  // fused in_proj: [xin | z] = xn @ w_in^T   (N=3072, K=768)
  gemm_gl<4, 128><<<dim3(2 * DI / 128, Mrows / 128, 1), 256, 0, stream>>>(
      Mrows, 2 * DI, DM, xn, DM, w_in, DM, buf1, z, DI, nullptr, flag);
  conv_silu_kernel<<<(Mrows * DI / 8) / 256, 256, 0, stream>>>(
      buf1, w_cv, w_cb, xc);
  // x_proj split-K=8 (klen=192): A=xc, B=w_x[128,1536] -> part8
  gemm_gl<0, 64><<<dim3(1, Mrows / 64, 8), 256, 0, stream>>>(
      Mrows, XD, DI / 8, xc, DI, w_x, DI, part8, nullptr, XD, nullptr, flag);
  reduce_xdbl<<<(Mrows * XD + 255) / 256, 256, 0, stream>>>(part8, xdbl, dtA);
  // delta = softplus(dtA @ w_dt^T + dt_b) -> buf1 (K padded to 64)
  gemm_gl<1, 64><<<dim3(DI / 128, Mrows / 64, 1), 256, 0, stream>>>(
      Mrows, DI, 64, dtA, 64, w_dt, 64, buf1, nullptr, DI, dt_b, flag);
  // chunked scan: p1 local, p2 carry prefix, p3 emit
  scan_p1<<<dim3(Bb * NC, DI / 64), 256, 0, stream>>>(
      buf1, xc, xdbl, A_log, carry_a, carry_b, flag);
  scan_p2<<<Bb * (DI / 64), 256, 0, stream>>>(carry_a, carry_b);
  scan_p3<<<dim3(Bb * NC, DI / 64), 256, 0, stream>>>(
      buf1, xc, xdbl, z, A_log, Dp, carry_b, flag);
  // convert out_proj into dead carry_a region, then out_proj split-K=2
  convert_w2<<<(NWO / 4 + 255) / 256, 256, 0, stream>>>(out_proj, w_out, flag);
  gemm_gl<0, 64><<<dim3(DM / 128, Mrows / 64, 2), 256, 0, stream>>>(
      Mrows, DM, DI / 2, buf1, DI, w_out, DI, part2, nullptr, DM, nullptr, flag);
  reduce_out<<<(Mrows * DM + 255) / 256, 256, 0, stream>>>(part2, x, out, flag);
}